// Round 6
// baseline (84.865 us; speedup 1.0000x reference)
//
#include <hip/hip_runtime.h>
#include <math.h>

typedef __attribute__((ext_vector_type(8))) short short8;
typedef __attribute__((ext_vector_type(4))) float f32x4;

#define BB 8192      // batch
#define CC 1000      // classes
#define NN 9192      // B + C real columns
#define NPAD 9216    // padded
#define DD 128       // feature dim
#define RB 64        // rows per block
#define NSPLIT 4     // column splits (blockIdx.y)
#define CPW 576      // columns per wave = 9216/(NSPLIT*4)
#define NT 18        // 32-col chunks per wave
#define K2F 14.426950408889634f   // (1/T) * log2(e)

// ---- workspace layout (float offsets) ----
#define WS_BSUM  0        // [64]
#define WS_CLS   64       // [1024] int
#define WS_TCOL  1088     // [9216] int
#define WS_RCP0  10304    // [9216]
#define WS_RCP1  19520    // [9216]
#define WS_SPART 28736    // [4*8192]
#define WS_PPART 61504    // [4*8192]
#define WS_FBF   94272    // F2: fragment-major bf16, 9216*128 shorts

static __device__ __forceinline__ unsigned short f2bf(float x) {
    unsigned int b = __float_as_uint(x);
    unsigned int r = (b + 0x7FFFu + ((b >> 16) & 1u)) >> 16;   // RNE
    return (unsigned short)r;
}

__global__ void hist_kernel(const int* __restrict__ tgt, int* __restrict__ cls) {
    int i = blockIdx.x * blockDim.x + threadIdx.x;
    if (i < BB) atomicAdd(&cls[tgt[i]], 1);
}

__global__ void prep_cols_kernel(const int* __restrict__ tgt, const int* __restrict__ cls,
                                 int* __restrict__ tcol, float* __restrict__ rcp0,
                                 float* __restrict__ rcp1) {
    int j = blockIdx.x * blockDim.x + threadIdx.x;
    if (j >= NPAD) return;
    if (j < NN) {
        int c = (j < BB) ? tgt[j] : (j - BB);
        int cnt = cls[c] + 1;                 // +1: the class center itself
        tcol[j] = c;
        rcp0[j] = 1.0f / (float)cnt;
        rcp1[j] = (cnt > 1) ? 1.0f / (float)(cnt - 1) : 0.0f;
    } else {
        tcol[j] = -2; rcp0[j] = 0.0f; rcp1[j] = 0.0f;
    }
}

// F2 fragment-major: 16B unit u = (j16*4 + ks)*64 + l4*16 + l15 holds
// (col j = j16*16+l15, k = ks*32 + l4*8 .. +8) as 8 bf16.  A wave's
// fragment load is then F2 + blk*1024B + lane*16B  (fully coalesced 1KB).
__global__ void cvt_kernel(const float* __restrict__ feats, const float* __restrict__ ctrs,
                           unsigned short* __restrict__ F2) {
    int u = blockIdx.x * 256 + threadIdx.x;       // one per 8 elements
    if (u >= NPAD * 16) return;
    int j = u >> 4, quad = u & 15;
    int k0 = quad * 8;
    float4 v0 = {0.f,0.f,0.f,0.f}, v1 = {0.f,0.f,0.f,0.f};
    if (j < BB) {
        v0 = *(const float4*)&feats[(size_t)j * DD + k0];
        v1 = *(const float4*)&feats[(size_t)j * DD + k0 + 4];
    } else if (j < NN) {
        v0 = *(const float4*)&ctrs[(size_t)(j - BB) * DD + k0];
        v1 = *(const float4*)&ctrs[(size_t)(j - BB) * DD + k0 + 4];
    }
    short8 o;
    o[0]=f2bf(v0.x); o[1]=f2bf(v0.y); o[2]=f2bf(v0.z); o[3]=f2bf(v0.w);
    o[4]=f2bf(v1.x); o[5]=f2bf(v1.y); o[6]=f2bf(v1.z); o[7]=f2bf(v1.w);
    size_t off = (size_t)((((j >> 4) * 4 + (quad >> 2)) * 64 + (quad & 3) * 16 + (j & 15)) * 8);
    *(short8*)&F2[off] = o;
}

static __device__ __forceinline__ void load_chunk(const unsigned short* __restrict__ F2,
                                                  int j0, int lane8, short8 (&buf)[8]) {
#pragma unroll
    for (int fn = 0; fn < 2; ++fn)
#pragma unroll
        for (int ks = 0; ks < 4; ++ks)
            buf[fn * 4 + ks] = *(const short8*)&F2[(size_t)(((((j0 >> 4) + fn) * 4 + ks) * 512) + lane8)];
}

template<bool DIAG>
static __device__ __forceinline__ void epilogue(const f32x4 (&acc)[4][2], const int (&ti)[16],
    const int (&tj)[2], const float (&r0)[2], const float (&r1)[2],
    int j0, int row0, int l15, int l4, float (&Sl)[16], float (&Pl)[16])
{
#pragma unroll
    for (int fm = 0; fm < 4; ++fm)
#pragma unroll
        for (int q = 0; q < 4; ++q) {
            const int t_i = ti[fm * 4 + q];
            const int i = row0 + fm * 16 + l4 * 4 + q;
            float s_add = 0.f, p_add = 0.f;
#pragma unroll
            for (int fn = 0; fn < 2; ++fn) {
                float d = acc[fm][fn][q];
                float l2 = fmaf(d, K2F, -K2F);           // (dot/T - 10)*log2e
                bool m = (tj[fn] == t_i);
                float e = exp2f(l2);
                if (DIAG) {
                    bool self = (j0 + fn * 16 + l15) == i;
                    if (self) { e = 0.f; m = false; }
                }
                s_add += e * (m ? r1[fn] : r0[fn]);      // padded cols: rcp=0
                p_add += m ? d : 0.f;                    // sum of masked dots
            }
            Sl[fm * 4 + q] += s_add;
            Pl[fm * 4 + q] += p_add;
        }
}

static __device__ __forceinline__ void compute_chunk(const short8 (&af)[4][4], const short8 (&buf)[8],
    const int* __restrict__ tcol, const float* __restrict__ rcp0, const float* __restrict__ rcp1,
    int j0, int row0, int l15, int l4, const int (&ti)[16], float (&Sl)[16], float (&Pl)[16])
{
    int tj[2]; float r0[2], r1[2];
#pragma unroll
    for (int fn = 0; fn < 2; ++fn) {
        int j = j0 + fn * 16 + l15;
        tj[fn] = tcol[j]; r0[fn] = rcp0[j]; r1[fn] = rcp1[j];
    }

    f32x4 acc[4][2];
    const f32x4 z4 = {0.f, 0.f, 0.f, 0.f};
#pragma unroll
    for (int fm = 0; fm < 4; ++fm)
#pragma unroll
        for (int fn = 0; fn < 2; ++fn)
            acc[fm][fn] = __builtin_amdgcn_mfma_f32_16x16x32_bf16(af[0][fm], buf[fn * 4], z4, 0, 0, 0);
#pragma unroll
    for (int ks = 1; ks < 4; ++ks)
#pragma unroll
        for (int fm = 0; fm < 4; ++fm)
#pragma unroll
            for (int fn = 0; fn < 2; ++fn)
                acc[fm][fn] = __builtin_amdgcn_mfma_f32_16x16x32_bf16(
                    af[ks][fm], buf[fn * 4 + ks], acc[fm][fn], 0, 0, 0);

    if ((unsigned)(j0 - row0) < 64u)
        epilogue<true>(acc, ti, tj, r0, r1, j0, row0, l15, l4, Sl, Pl);
    else
        epilogue<false>(acc, ti, tj, r0, r1, j0, row0, l15, l4, Sl, Pl);
}

__global__ __launch_bounds__(256, 2) void main_kernel(
    const unsigned short* __restrict__ F2, const int* __restrict__ tcol,
    const float* __restrict__ rcp0, const float* __restrict__ rcp1,
    float* __restrict__ S_part, float* __restrict__ P_part)
{
    __shared__ float combS[3][64], combP[3][64];

    const int tid  = threadIdx.x;
    const int lane = tid & 63;
    const int wave = tid >> 6;
    const int l15 = lane & 15, l4 = lane >> 4;
    const int lane8 = lane * 8;
    const int row0 = blockIdx.x * RB;
    const int split = blockIdx.y;
    const int cb = (split * 4 + wave) * CPW;     // this wave's column base

    // ---- A fragments straight from global (rows row0..row0+63) ----
    short8 af[4][4];                             // [ks][fm]
#pragma unroll
    for (int fm = 0; fm < 4; ++fm)
#pragma unroll
        for (int ks = 0; ks < 4; ++ks)
            af[ks][fm] = *(const short8*)&F2[(size_t)(((((row0 >> 4) + fm) * 4 + ks) * 512) + lane8)];

    int ti[16];
#pragma unroll
    for (int fm = 0; fm < 4; ++fm)
#pragma unroll
        for (int q = 0; q < 4; ++q)
            ti[fm * 4 + q] = tcol[row0 + fm * 16 + l4 * 4 + q];

    float Sl[16], Pl[16];
#pragma unroll
    for (int x = 0; x < 16; ++x) { Sl[x] = 0.f; Pl[x] = 0.f; }

    short8 bA[8], bB[8];
    load_chunk(F2, cb, lane8, bA);

#pragma unroll 1
    for (int tt = 0; tt < NT; tt += 2) {
        if (tt + 1 < NT) load_chunk(F2, cb + (tt + 1) * 32, lane8, bB);
        compute_chunk(af, bA, tcol, rcp0, rcp1, cb + tt * 32, row0, l15, l4, ti, Sl, Pl);
        if (tt + 2 < NT) load_chunk(F2, cb + (tt + 2) * 32, lane8, bA);
        compute_chunk(af, bB, tcol, rcp0, rcp1, cb + (tt + 1) * 32, row0, l15, l4, ti, Sl, Pl);
    }

    // ---- 16-lane column reduce (tree), then cross-wave combine via tiny LDS ----
#pragma unroll
    for (int idx = 0; idx < 16; ++idx) {
        float S = Sl[idx], P = Pl[idx];
#pragma unroll
        for (int off = 1; off < 16; off <<= 1) {
            S += __shfl_xor(S, off, 64);
            P += __shfl_xor(P, off, 64);
        }
        Sl[idx] = S; Pl[idx] = P;
        if (wave > 0 && l15 == 0) {
            int rl = (idx >> 2) * 16 + l4 * 4 + (idx & 3);
            combS[wave - 1][rl] = S; combP[wave - 1][rl] = P;
        }
    }
    __syncthreads();
    if (wave == 0 && l15 == 0) {
#pragma unroll
        for (int idx = 0; idx < 16; ++idx) {
            int rl = (idx >> 2) * 16 + l4 * 4 + (idx & 3);
            int row = row0 + rl;
            S_part[split * BB + row] = Sl[idx] + combS[0][rl] + combS[1][rl] + combS[2][rl];
            P_part[split * BB + row] = Pl[idx] + combP[0][rl] + combP[1][rl] + combP[2][rl];
        }
    }
}

__global__ void finalize_kernel(const int* __restrict__ cls, const int* __restrict__ tcol,
                                const float* __restrict__ S_part, const float* __restrict__ P_part,
                                float* __restrict__ bsum)
{
    const int i = blockIdx.x * 256 + threadIdx.x;
    float S = 0.f, Pd = 0.f;
#pragma unroll
    for (int s = 0; s < NSPLIT; ++s) {
        S  += S_part[s * BB + i];
        Pd += P_part[s * BB + i];
    }
    const float npos = (float)cls[tcol[i]];
    // P(sum of l2) = K2F*Pd - K2F*npos  ->  P/npos = K2F*Pd/npos - K2F
    float lp = fmaf(K2F, Pd / npos, -K2F) - log2f(S);   // log2 units

    float v = lp;
#pragma unroll
    for (int off = 1; off < 64; off <<= 1) v += __shfl_xor(v, off, 64);
    __shared__ float wsum[4];
    if ((threadIdx.x & 63) == 0) wsum[threadIdx.x >> 6] = v;
    __syncthreads();
    if (threadIdx.x == 0) bsum[blockIdx.x] = wsum[0] + wsum[1] + wsum[2] + wsum[3];
}

__global__ void out_kernel(const float* __restrict__ bsum, float* __restrict__ out) {
    const int t = threadIdx.x;   // 64 threads
    float v = (t < 32) ? bsum[t] : 0.f;
#pragma unroll
    for (int off = 1; off < 64; off <<= 1) v += __shfl_xor(v, off, 64);
    if (t == 0) out[0] = -0.6931471805599453f * (v / (float)BB);   // ln2 * mean, negated
}

extern "C" void kernel_launch(void* const* d_in, const int* in_sizes, int n_in,
                              void* d_out, int out_size, void* d_ws, size_t ws_size,
                              hipStream_t stream) {
    const float* ctrs  = (const float*)d_in[0];   // centers1 [1000,128]
    const float* feats = (const float*)d_in[1];   // features [8192,128]
    const int*   tgt   = (const int*)d_in[2];     // targets  [8192] int32
    float* out = (float*)d_out;
    float* ws  = (float*)d_ws;

    int*   cls  = (int*)(ws + WS_CLS);
    int*   tcol = (int*)(ws + WS_TCOL);
    float* rcp0 = ws + WS_RCP0;
    float* rcp1 = ws + WS_RCP1;
    float* Sp   = ws + WS_SPART;
    float* Pp   = ws + WS_PPART;
    float* bsum = ws + WS_BSUM;
    unsigned short* F2 = (unsigned short*)(ws + WS_FBF);

    hipMemsetAsync(d_ws, 0, (64 + 1024) * sizeof(float), stream);
    hist_kernel<<<dim3(BB / 256), dim3(256), 0, stream>>>(tgt, cls);
    prep_cols_kernel<<<dim3(NPAD / 256), dim3(256), 0, stream>>>(tgt, cls, tcol, rcp0, rcp1);
    cvt_kernel<<<dim3(NPAD * 16 / 256), dim3(256), 0, stream>>>(feats, ctrs, F2);
    main_kernel<<<dim3(BB / RB, NSPLIT), dim3(256), 0, stream>>>(F2, tcol, rcp0, rcp1, Sp, Pp);
    finalize_kernel<<<dim3(BB / 256), dim3(256), 0, stream>>>(cls, tcol, Sp, Pp, bsum);
    out_kernel<<<dim3(1), dim3(64), 0, stream>>>(bsum, out);
}